// Round 12
// baseline (332.133 us; speedup 1.0000x reference)
//
#include <hip/hip_runtime.h>
#include <hip/hip_bf16.h>

typedef __attribute__((ext_vector_type(8))) short bf16x8;
typedef __attribute__((ext_vector_type(4))) float f32x4;

#define DH 128
#define DOUT 64

static __device__ __forceinline__ unsigned short f2bf(float f) {
    __hip_bfloat16 h = __float2bfloat16(f);
    return *(unsigned short*)&h;
}
static __device__ __forceinline__ float2 bfp2f(unsigned int u) {
    float2 r;
    r.x = __uint_as_float(u << 16);
    r.y = __uint_as_float(u & 0xffff0000u);
    return r;
}

// ---------------- prep + hist fused (cnt pre-zeroed via hipMemsetAsync) ----------------

struct WPrep {
    const float* src[8];
    unsigned short* dst[8];
};

__global__ void prep_hist_kernel(const float* __restrict__ x, unsigned short* __restrict__ xb,
                                 int n4, WPrep p,
                                 const int* __restrict__ dstv, int* __restrict__ cnt,
                                 int* __restrict__ rank, int E, int N_) {
    int id = blockIdx.x * blockDim.x + threadIdx.x;
    if (id < n4) {
        float4 v = ((const float4*)x)[id];
        ushort4 b;
        b.x = f2bf(v.x); b.y = f2bf(v.y); b.z = f2bf(v.z); b.w = f2bf(v.w);
        ((ushort4*)xb)[id] = b;
        return;
    }
    id -= n4;
    if (id < 7 * 16384 + 8192) {
        int m, off;
        if (id < 7 * 16384) { m = id >> 14; off = id & 16383; }
        else { m = 7; off = id - 7 * 16384; }
        int shift = (m == 7) ? 6 : 7;
        int nc = 1 << shift;
        int k = off >> shift;
        int n = off & (nc - 1);
        p.dst[m][n * 128 + k] = f2bf(p.src[m][off]);
        return;
    }
    id -= 7 * 16384 + 8192;
    if (id < E) {
        int d = dstv[id];
        if ((unsigned)d < (unsigned)N_) rank[id] = atomicAdd(&cnt[d], 1);
    }
}

// ---------------- CSR build (exact degrees; esrc holds element offsets src*64) ----------------

__global__ void scan1_kernel(const int* __restrict__ cnt, int* __restrict__ rp_part,
                             int* __restrict__ bsum, int n) {
    __shared__ int s[256];
    int tid = threadIdx.x;
    int i = blockIdx.x * 256 + tid;
    int v = (i < n) ? cnt[i] : 0;
    s[tid] = v;
    __syncthreads();
    for (int off = 1; off < 256; off <<= 1) {
        int t = (tid >= off) ? s[tid - off] : 0;
        __syncthreads();
        s[tid] += t;
        __syncthreads();
    }
    if (i <= n) rp_part[i] = s[tid] - v;
    if (tid == 255) bsum[blockIdx.x] = s[255];
}

// row_ptr finalize + edge fill; each block re-derives the bsum prefix in LDS (nb <= 256)
__global__ void scan3_fill_kernel(const int* __restrict__ rp_part, const int* __restrict__ bsum,
                                  int* __restrict__ row_ptr,
                                  const int* __restrict__ src, const int* __restrict__ dst,
                                  const int* __restrict__ rank, int* __restrict__ esrc,
                                  int n, int E, int nb) {
    __shared__ int sb[256];
    int tid = threadIdx.x;
    {
        int v = (tid < nb) ? bsum[tid] : 0;
        sb[tid] = v;
        __syncthreads();
        for (int off = 1; off < 256; off <<= 1) {
            int t = (tid >= off) ? sb[tid - off] : 0;
            __syncthreads();
            sb[tid] += t;
            __syncthreads();
        }
        int incl = sb[tid];
        __syncthreads();
        sb[tid] = incl - v;  // exclusive prefix
        __syncthreads();
    }
    int gid = blockIdx.x * 256 + tid;
    if (gid <= n) row_ptr[gid] = rp_part[gid] + sb[gid >> 8];
    if (gid < E) {
        int d = dst[gid];
        if ((unsigned)d < (unsigned)n)
            esrc[rp_part[d] + sb[d >> 8] + rank[gid]] = src[gid] * 64;  // uint-element offset
    }
}

// ---------------- fused layer: agg -> GEMM1(relu) -> GEMM2 [-> GEMM3(relu) -> GEMM4] ----------------
// 16-row M tile, 256 threads (4 waves). Gather is the r5-measured codegen (54 us/layer):
// hb = (uint*)h + lane; esrc holds src*64; 8/2/1 exact-bounds batches; float2 accumulate.
// NOTE: this code is codegen-sensitive — "equivalent" rewrites (byte offsets, min-clamp,
// uint accumulate) emitted VGPR=28 and ran 27% slower (r11). Do not "simplify".

template <bool HEAD>
__launch_bounds__(256, 8)
__global__ void layer_kernel(const unsigned short* __restrict__ h,
                             const int* __restrict__ rp,
                             const int* __restrict__ esrc,
                             const unsigned short* __restrict__ W1t,
                             const float* __restrict__ b1,
                             const unsigned short* __restrict__ W2t,
                             const float* __restrict__ b2,
                             const unsigned short* __restrict__ W3t,
                             const float* __restrict__ b3,
                             const unsigned short* __restrict__ W4t,
                             const float* __restrict__ b4,
                             void* __restrict__ outp, int M) {
    constexpr int LDA = 128 + 8;
    __shared__ __align__(16) unsigned short As[16][LDA];
    __shared__ __align__(16) unsigned short Zs[16][LDA];

    int tid = threadIdx.x;
    int wave = __builtin_amdgcn_readfirstlane(tid >> 6);
    int lane = tid & 63;
    int row0 = blockIdx.x * 16;

    const unsigned int* hb = (const unsigned int*)h + lane;  // + node*64 indexes row

    // ---- gather: wave handles 4 rows (exact r5 structure) ----
    for (int i = 0; i < 4; ++i) {
        int r = wave * 4 + i;
        int node = row0 + r;
        float2 acc = make_float2(0.f, 0.f);
        if (node < M) {
            acc = bfp2f(hb[node * 64]);
            int b = rp[node], e = rp[node + 1];
            int j = b;
            for (; j + 8 <= e; j += 8) {
                unsigned int v0 = hb[esrc[j + 0]];
                unsigned int v1 = hb[esrc[j + 1]];
                unsigned int v2 = hb[esrc[j + 2]];
                unsigned int v3 = hb[esrc[j + 3]];
                unsigned int v4 = hb[esrc[j + 4]];
                unsigned int v5 = hb[esrc[j + 5]];
                unsigned int v6 = hb[esrc[j + 6]];
                unsigned int v7 = hb[esrc[j + 7]];
                float2 f0 = bfp2f(v0), f1 = bfp2f(v1), f2 = bfp2f(v2), f3 = bfp2f(v3);
                float2 f4 = bfp2f(v4), f5 = bfp2f(v5), f6 = bfp2f(v6), f7 = bfp2f(v7);
                acc.x += ((f0.x + f1.x) + (f2.x + f3.x)) +
                         ((f4.x + f5.x) + (f6.x + f7.x));
                acc.y += ((f0.y + f1.y) + (f2.y + f3.y)) +
                         ((f4.y + f5.y) + (f6.y + f7.y));
            }
            for (; j + 2 <= e; j += 2) {
                unsigned int v0 = hb[esrc[j]];
                unsigned int v1 = hb[esrc[j + 1]];
                float2 f0 = bfp2f(v0), f1 = bfp2f(v1);
                acc.x += f0.x + f1.x;
                acc.y += f0.y + f1.y;
            }
            for (; j < e; ++j) {
                float2 f0 = bfp2f(hb[esrc[j]]);
                acc.x += f0.x;
                acc.y += f0.y;
            }
        }
        unsigned int pv = (unsigned int)f2bf(acc.x) | ((unsigned int)f2bf(acc.y) << 16);
        *(unsigned int*)&As[r][lane * 2] = pv;
    }
    __syncthreads();

    int quad = lane >> 4;
    int l16 = lane & 15;

    // ---- GEMM1: Zs = relu(As @ W1 + b1) ----
    bf16x8 af[4];
#pragma unroll
    for (int kt = 0; kt < 4; ++kt)
        af[kt] = *(const bf16x8*)(&As[l16][kt * 32 + quad * 8]);
#pragma unroll
    for (int p = 0; p < 2; ++p) {
        int ncol = (wave * 2 + p) * 16 + l16;
        const unsigned short* wp = W1t + ncol * 128 + quad * 8;
        f32x4 a = {0.f, 0.f, 0.f, 0.f};
#pragma unroll
        for (int kt = 0; kt < 4; ++kt)
            a = __builtin_amdgcn_mfma_f32_16x16x32_bf16(
                af[kt], *(const bf16x8*)(wp + kt * 32), a, 0, 0, 0);
        float bs = b1[ncol];
#pragma unroll
        for (int r = 0; r < 4; ++r) {
            float v = a[r] + bs;
            if (v < 0.f) v = 0.f;
            Zs[quad * 4 + r][ncol] = f2bf(v);
        }
    }
    __syncthreads();

    // ---- GEMM2: relu(Zs @ W2 + b2) -> global bf16 (conv) or As (head) ----
    bf16x8 zf[4];
#pragma unroll
    for (int kt = 0; kt < 4; ++kt)
        zf[kt] = *(const bf16x8*)(&Zs[l16][kt * 32 + quad * 8]);
#pragma unroll
    for (int p = 0; p < 2; ++p) {
        int ncol = (wave * 2 + p) * 16 + l16;
        const unsigned short* wp = W2t + ncol * 128 + quad * 8;
        f32x4 a = {0.f, 0.f, 0.f, 0.f};
#pragma unroll
        for (int kt = 0; kt < 4; ++kt)
            a = __builtin_amdgcn_mfma_f32_16x16x32_bf16(
                zf[kt], *(const bf16x8*)(wp + kt * 32), a, 0, 0, 0);
        float bs = b2[ncol];
#pragma unroll
        for (int r = 0; r < 4; ++r) {
            float v = a[r] + bs;
            if (v < 0.f) v = 0.f;
            if (HEAD) {
                As[quad * 4 + r][ncol] = f2bf(v);
            } else {
                int grow = row0 + quad * 4 + r;
                if (grow < M)
                    ((unsigned short*)outp)[(size_t)grow * 128 + ncol] = f2bf(v);
            }
        }
    }

    if (HEAD) {
        __syncthreads();
        // ---- GEMM3: Zs = relu(As @ W3 + b3) ----
        bf16x8 hf[4];
#pragma unroll
        for (int kt = 0; kt < 4; ++kt)
            hf[kt] = *(const bf16x8*)(&As[l16][kt * 32 + quad * 8]);
#pragma unroll
        for (int p = 0; p < 2; ++p) {
            int ncol = (wave * 2 + p) * 16 + l16;
            const unsigned short* wp = W3t + ncol * 128 + quad * 8;
            f32x4 a = {0.f, 0.f, 0.f, 0.f};
#pragma unroll
            for (int kt = 0; kt < 4; ++kt)
                a = __builtin_amdgcn_mfma_f32_16x16x32_bf16(
                    hf[kt], *(const bf16x8*)(wp + kt * 32), a, 0, 0, 0);
            float bs = b3[ncol];
#pragma unroll
            for (int r = 0; r < 4; ++r) {
                float v = a[r] + bs;
                if (v < 0.f) v = 0.f;
                Zs[quad * 4 + r][ncol] = f2bf(v);
            }
        }
        __syncthreads();
        // ---- GEMM4: d_out = Zs @ W4 + b4 (fp32, 64 cols) ----
        bf16x8 gf[4];
#pragma unroll
        for (int kt = 0; kt < 4; ++kt)
            gf[kt] = *(const bf16x8*)(&Zs[l16][kt * 32 + quad * 8]);
        {
            int ncol = wave * 16 + l16;
            const unsigned short* wp = W4t + ncol * 128 + quad * 8;
            f32x4 a = {0.f, 0.f, 0.f, 0.f};
#pragma unroll
            for (int kt = 0; kt < 4; ++kt)
                a = __builtin_amdgcn_mfma_f32_16x16x32_bf16(
                    gf[kt], *(const bf16x8*)(wp + kt * 32), a, 0, 0, 0);
            float bs = b4[ncol];
#pragma unroll
            for (int r = 0; r < 4; ++r) {
                int grow = row0 + quad * 4 + r;
                if (grow < M)
                    ((float*)outp)[(size_t)grow * 64 + ncol] = a[r] + bs;
            }
        }
    }
}

// ---------------- launch ----------------

extern "C" void kernel_launch(void* const* d_in, const int* in_sizes, int n_in,
                              void* d_out, int out_size, void* d_ws, size_t ws_size,
                              hipStream_t stream) {
    const float* x = (const float*)d_in[0];
    const int* ei = (const int*)d_in[1];
    int N = in_sizes[0] / DH;
    int E = in_sizes[1] / 2;
    const int* src = ei;
    const int* dstv = ei + E;

    char* ws = (char*)d_ws;
    size_t off = 0;
    auto alloc = [&](size_t bytes) -> void* {
        void* p = ws + off;
        off += (bytes + 255) & ~(size_t)255;
        return p;
    };
    unsigned short* xb = (unsigned short*)alloc((size_t)N * DH * 2);
    unsigned short* hA = (unsigned short*)alloc((size_t)N * DH * 2);
    unsigned short* hB = (unsigned short*)alloc((size_t)N * DH * 2);
    unsigned short* wt[8];
    for (int m = 0; m < 8; ++m) wt[m] = (unsigned short*)alloc(16384 * 2);
    int* cnt     = (int*)alloc((size_t)N * 4);
    int* rp_part = (int*)alloc((size_t)(N + 1) * 4);
    int* row_ptr = (int*)alloc((size_t)(N + 1) * 4);
    int* rank    = (int*)alloc((size_t)E * 4);
    int* bsum    = (int*)alloc(256 * 4);
    int* esrc    = (int*)alloc((size_t)E * 4);

    WPrep wp;
    wp.src[0] = (const float*)d_in[2];
    wp.src[1] = (const float*)d_in[4];
    wp.src[2] = (const float*)d_in[6];
    wp.src[3] = (const float*)d_in[8];
    wp.src[4] = (const float*)d_in[10];
    wp.src[5] = (const float*)d_in[12];
    wp.src[6] = (const float*)d_in[14];
    wp.src[7] = (const float*)d_in[16];
    for (int m = 0; m < 8; ++m) wp.dst[m] = wt[m];

    hipMemsetAsync(cnt, 0, (size_t)N * 4, stream);

    int n4 = N * DH / 4;
    int prep_items = n4 + 7 * 16384 + 8192 + E;
    prep_hist_kernel<<<(prep_items + 255) / 256, 256, 0, stream>>>(
        x, xb, n4, wp, dstv, cnt, rank, E, N);

    int nb = (N + 255) / 256;           // blocks over nodes (for bsum indexing)
    int nb1 = (N + 1 + 255) / 256;      // covers gid == n
    int eb = (E + 255) / 256;
    scan1_kernel<<<nb1, 256, 0, stream>>>(cnt, rp_part, bsum, N);
    int s3blocks = eb > nb1 ? eb : nb1;
    scan3_fill_kernel<<<s3blocks, 256, 0, stream>>>(rp_part, bsum, row_ptr,
                                                    src, dstv, rank, esrc, N, E, nb);

    int gb = (N + 15) / 16;

    const float* c1b1 = (const float*)d_in[3];
    const float* c1b2 = (const float*)d_in[5];
    const float* c2b1 = (const float*)d_in[7];
    const float* c2b2 = (const float*)d_in[9];
    const float* c3b1 = (const float*)d_in[11];
    const float* c3b2 = (const float*)d_in[13];
    const float* l1b  = (const float*)d_in[15];
    const float* l2b  = (const float*)d_in[17];

    layer_kernel<false><<<gb, 256, 0, stream>>>(
        xb, row_ptr, esrc, wt[0], c1b1, wt[1], c1b2,
        nullptr, nullptr, nullptr, nullptr, hA, N);
    layer_kernel<false><<<gb, 256, 0, stream>>>(
        hA, row_ptr, esrc, wt[2], c2b1, wt[3], c2b2,
        nullptr, nullptr, nullptr, nullptr, hB, N);
    layer_kernel<true><<<gb, 256, 0, stream>>>(
        hB, row_ptr, esrc, wt[4], c3b1, wt[5], c3b2,
        wt[6], l1b, wt[7], l2b, d_out, N);
}